// Round 3
// baseline (163.811 us; speedup 1.0000x reference)
//
#include <hip/hip_runtime.h>
#include <hip/hip_bf16.h>

#define IN_F 4096
#define OUT_F 11008
#define TOKENS 32
#define RANK 16
#define KSPLIT 4
#define KSLICE (IN_F / KSPLIT)  // 1024
#define OUT_ELEMS (TOKENS * OUT_F)  // 352256

typedef unsigned short u16;
typedef __attribute__((ext_vector_type(8))) short bf16x8;
typedef __attribute__((ext_vector_type(4))) float f32x4;

__device__ const float NF4_d[16] = {
    -1.0f, -0.6961928009986877f, -0.5250730514526367f, -0.39491748809814453f,
    -0.28444138169288635f, -0.18477343022823334f, -0.09105003625154495f, 0.0f,
    0.07958029955625534f, 0.16093020141124725f, 0.24611230194568634f,
    0.33791524171829224f, 0.44070982933044434f, 0.5626170039176941f,
    0.7229568362236023f, 1.0f};

static __device__ __forceinline__ unsigned pk2(float a, float b) {
    __hip_bfloat162 h = __float22bfloat162_rn(make_float2(a, b));
    unsigned u;
    __builtin_memcpy(&u, &h, 4);
    return u;
}

// byte b (0..255) -> two scaled bf16 codes, via lane-crossbar (no LDS banks)
static __device__ __forceinline__ unsigned dq_byte(int b, int codei, float sc) {
    int ih = (b >> 2) & 0x3C;  // (b>>4)*4
    int il = (b << 2) & 0x3C;  // (b&15)*4
    float h = __int_as_float(__builtin_amdgcn_ds_bpermute(ih, codei));
    float l = __int_as_float(__builtin_amdgcn_ds_bpermute(il, codei));
    return pk2(h * sc, l * sc);
}

// prep: blocks 0..511 compute xa[t][r]; blocks 512..639 convert x -> bf16
__global__ void prep(const float* __restrict__ x, const float* __restrict__ A,
                     u16* __restrict__ xbf, float* __restrict__ xa) {
    __shared__ float red[256];
    if (blockIdx.x >= 512) {
        int i4 = (blockIdx.x - 512) * 256 + threadIdx.x;  // 32768 float4s
        float4 v = ((const float4*)x)[i4];
        uint2 o;
        o.x = pk2(v.x, v.y);
        o.y = pk2(v.z, v.w);
        ((uint2*)xbf)[i4] = o;
        return;
    }
    int b = blockIdx.x;  // 0..511
    int t = b >> 4, r = b & 15;
    const float4* xr = (const float4*)(x + t * IN_F);
    const float4* ar = (const float4*)(A + r * IN_F);
    float s = 0.f;
    for (int c = 0; c < 4; ++c) {
        int j = c * 256 + threadIdx.x;
        float4 xv = xr[j], av = ar[j];
        s += xv.x * av.x + xv.y * av.y + xv.z * av.z + xv.w * av.w;
    }
    red[threadIdx.x] = s;
    __syncthreads();
    for (int st = 128; st > 0; st >>= 1) {
        if (threadIdx.x < st) red[threadIdx.x] += red[threadIdx.x + st];
        __syncthreads();
    }
    if (threadIdx.x == 0) xa[b] = red[0];
}

// qlora_part: NF4 dequant + bf16 MFMA; partials to ws (no LDS, no barriers)
__global__ __launch_bounds__(256) void qlora_part(const int* __restrict__ packed,
                                                  const float* __restrict__ scales,
                                                  const u16* __restrict__ xbf,
                                                  float* __restrict__ part) {
    const int tid = threadIdx.x;
    const int lane = tid & 63;
    const int wv = tid >> 6;
    const int n = lane & 15;  // output col within 16-tile / token row of A
    const int q = lane >> 4;  // k-subblock
    const int kbase = blockIdx.y * KSLICE;
    const int o = blockIdx.x * 64 + wv * 16 + n;

    const int codei = __float_as_int(NF4_d[lane & 15]);

    // step s reads int4 at (packed + o*2048 + kbase/2) int4-index s*4 + q
    const int4* ppq = (const int4*)(packed + o * 2048 + (kbase >> 1)) + q;
    const u16* xq0 = xbf + n * IN_F + kbase + q * 8;
    const u16* xq1 = xq0 + 16 * IN_F;
    const float* sg = scales + o * 64 + (kbase >> 6);

    f32x4 acc0 = {0.f, 0.f, 0.f, 0.f};
    f32x4 acc1 = {0.f, 0.f, 0.f, 0.f};

    int4 c0 = ppq[0];
    int4 c1 = ppq[4];

#pragma unroll
    for (int s = 0; s < 32; s += 2) {
        int4 n0 = c0, n1 = c1;
        if (s + 2 < 32) {
            n0 = ppq[(s + 2) * 4];
            n1 = ppq[(s + 3) * 4];
        }
        float sc = sg[s >> 1];  // same 64-group for steps s, s+1

        {
            uint4 bu;
            bu.x = dq_byte(c0.x, codei, sc);
            bu.y = dq_byte(c0.y, codei, sc);
            bu.z = dq_byte(c0.z, codei, sc);
            bu.w = dq_byte(c0.w, codei, sc);
            bf16x8 bfrag;
            __builtin_memcpy(&bfrag, &bu, 16);
            bf16x8 a0 = *(const bf16x8*)(xq0 + s * 32);
            bf16x8 a1 = *(const bf16x8*)(xq1 + s * 32);
            acc0 = __builtin_amdgcn_mfma_f32_16x16x32_bf16(a0, bfrag, acc0, 0, 0, 0);
            acc1 = __builtin_amdgcn_mfma_f32_16x16x32_bf16(a1, bfrag, acc1, 0, 0, 0);
        }
        {
            uint4 bu;
            bu.x = dq_byte(c1.x, codei, sc);
            bu.y = dq_byte(c1.y, codei, sc);
            bu.z = dq_byte(c1.z, codei, sc);
            bu.w = dq_byte(c1.w, codei, sc);
            bf16x8 bfrag;
            __builtin_memcpy(&bfrag, &bu, 16);
            bf16x8 a0 = *(const bf16x8*)(xq0 + (s + 1) * 32);
            bf16x8 a1 = *(const bf16x8*)(xq1 + (s + 1) * 32);
            acc0 = __builtin_amdgcn_mfma_f32_16x16x32_bf16(a0, bfrag, acc0, 0, 0, 0);
            acc1 = __builtin_amdgcn_mfma_f32_16x16x32_bf16(a1, bfrag, acc1, 0, 0, 0);
        }
        c0 = n0;
        c1 = n1;
    }

    // C/D layout: col = lane&15 (o), row = (lane>>4)*4 + reg (token)
    float* pb = part + blockIdx.y * OUT_ELEMS + o;
    for (int r = 0; r < 4; ++r) {
        int t = q * 4 + r;
        pb[t * OUT_F] = acc0[r];
        pb[(t + 16) * OUT_F] = acc1[r];
    }
}

// reduce_lora: out = sum of 4 partials + (xa @ B^T)
__global__ void reduce_lora(const float* __restrict__ part,
                            const float* __restrict__ xa,
                            const float* __restrict__ B,
                            float* __restrict__ out) {
    int idx = blockIdx.x * 256 + threadIdx.x;  // 352256 total
    int t = idx / OUT_F;
    int o = idx - t * OUT_F;
    float s = part[idx] + part[idx + OUT_ELEMS] + part[idx + 2 * OUT_ELEMS] +
              part[idx + 3 * OUT_ELEMS];
    const float4* br = (const float4*)(B + o * RANK);
    const float4* xr = (const float4*)(xa + t * RANK);
    float acc = 0.f;
    for (int c = 0; c < 4; ++c) {
        float4 bv = br[c], xv = xr[c];
        acc += bv.x * xv.x + bv.y * xv.y + bv.z * xv.z + bv.w * xv.w;
    }
    out[idx] = s + acc;  // SCALING = 1.0
}

extern "C" void kernel_launch(void* const* d_in, const int* in_sizes, int n_in,
                              void* d_out, int out_size, void* d_ws, size_t ws_size,
                              hipStream_t stream) {
    const float* x = (const float*)d_in[0];
    const int* packed = (const int*)d_in[1];
    const float* scales = (const float*)d_in[2];
    const float* lora_A = (const float*)d_in[3];
    const float* lora_B = (const float*)d_in[4];
    float* out = (float*)d_out;

    u16* xbf = (u16*)d_ws;                                   // 262144 B
    float* xa = (float*)((char*)d_ws + 262144);              // 2048 B
    float* part = (float*)((char*)d_ws + 264192);            // 4 x 1.409 MB

    prep<<<640, 256, 0, stream>>>(x, lora_A, xbf, xa);
    qlora_part<<<dim3(OUT_F / 64, KSPLIT), 256, 0, stream>>>(packed, scales, xbf, part);
    reduce_lora<<<OUT_ELEMS / 256, 256, 0, stream>>>(part, xa, lora_B, out);
}

// Round 4
// 158.543 us; speedup vs baseline: 1.0332x; 1.0332x over previous
//
#include <hip/hip_runtime.h>
#include <hip/hip_bf16.h>

#define IN_F 4096
#define OUT_F 11008
#define TOKENS 32
#define RANK 16
#define KSPLIT 8
#define KSLICE (IN_F / KSPLIT)  // 512
#define XPAD 520                // u16 per LDS x-row (512 data + 8 pad)

typedef unsigned short u16;
typedef __attribute__((ext_vector_type(8))) short bf16x8;
typedef __attribute__((ext_vector_type(4))) float f32x4;

__device__ const float NF4_d[16] = {
    -1.0f, -0.6961928009986877f, -0.5250730514526367f, -0.39491748809814453f,
    -0.28444138169288635f, -0.18477343022823334f, -0.09105003625154495f, 0.0f,
    0.07958029955625534f, 0.16093020141124725f, 0.24611230194568634f,
    0.33791524171829224f, 0.44070982933044434f, 0.5626170039176941f,
    0.7229568362236023f, 1.0f};

static __device__ __forceinline__ unsigned pk2(float a, float b) {
    __hip_bfloat162 h = __float22bfloat162_rn(make_float2(a, b));
    unsigned u;
    __builtin_memcpy(&u, &h, 4);
    return u;
}

// prep: blocks 0..511 compute xa[t][r]; blocks 512..639 convert x -> bf16
__global__ void prep(const float* __restrict__ x, const float* __restrict__ A,
                     u16* __restrict__ xbf, float* __restrict__ xa) {
    __shared__ float red[256];
    if (blockIdx.x >= 512) {
        int i4 = (blockIdx.x - 512) * 256 + threadIdx.x;  // 32768 float4s
        float4 v = ((const float4*)x)[i4];
        uint2 o;
        o.x = pk2(v.x, v.y);
        o.y = pk2(v.z, v.w);
        ((uint2*)xbf)[i4] = o;
        return;
    }
    int b = blockIdx.x;  // 0..511
    int t = b >> 4, r = b & 15;
    const float4* xr = (const float4*)(x + t * IN_F);
    const float4* ar = (const float4*)(A + r * IN_F);
    float s = 0.f;
    for (int c = 0; c < 4; ++c) {
        int j = c * 256 + threadIdx.x;
        float4 xv = xr[j], av = ar[j];
        s += xv.x * av.x + xv.y * av.y + xv.z * av.z + xv.w * av.w;
    }
    red[threadIdx.x] = s;
    __syncthreads();
    for (int st = 128; st > 0; st >>= 1) {
        if (threadIdx.x < st) red[threadIdx.x] += red[threadIdx.x + st];
        __syncthreads();
    }
    if (threadIdx.x == 0) xa[b] = red[0];
}

// lora_out: out[t][o..o+3] = xa[t][:] . B[o..o+3][:]   (initializes out)
__global__ void lora_out(const float* __restrict__ xa, const float* __restrict__ B,
                         float* __restrict__ out) {
    int idx4 = blockIdx.x * 256 + threadIdx.x;  // 88064 total
    int t = idx4 / (OUT_F / 4);
    int o4 = idx4 - t * (OUT_F / 4);
    const float4* br = (const float4*)(B + o4 * 4 * RANK);  // 4 rows x 16 floats
    const float4* xr = (const float4*)(xa + t * RANK);
    float4 xv0 = xr[0], xv1 = xr[1], xv2 = xr[2], xv3 = xr[3];
    float res[4];
#pragma unroll
    for (int j = 0; j < 4; ++j) {
        float4 b0 = br[j * 4 + 0], b1 = br[j * 4 + 1];
        float4 b2 = br[j * 4 + 2], b3 = br[j * 4 + 3];
        res[j] = b0.x * xv0.x + b0.y * xv0.y + b0.z * xv0.z + b0.w * xv0.w +
                 b1.x * xv1.x + b1.y * xv1.y + b1.z * xv1.z + b1.w * xv1.w +
                 b2.x * xv2.x + b2.y * xv2.y + b2.z * xv2.z + b2.w * xv2.w +
                 b3.x * xv3.x + b3.y * xv3.y + b3.z * xv3.z + b3.w * xv3.w;
    }
    float4 r4 = make_float4(res[0], res[1], res[2], res[3]);
    *(float4*)(out + t * OUT_F + o4 * 4) = r4;  // SCALING = 1.0
}

// main: NF4 dequant + bf16 MFMA GEMM, K-split partials via atomicAdd
__global__ __launch_bounds__(256, 4) void qlora_main(const int* __restrict__ packed,
                                                     const float* __restrict__ scales,
                                                     const u16* __restrict__ xbf,
                                                     float* __restrict__ out) {
    __shared__ u16 xs[32 * XPAD];  // 32 tokens x 512 k (bf16), padded rows
    __shared__ unsigned tbl[256];  // byte -> packed bf16 (lo16=lo_code, hi16=hi_code)
    const int tid = threadIdx.x;
    const int kbase = blockIdx.y * KSLICE;
    const int obase = blockIdx.x * 64;

    const int lane = tid & 63;
    const int wv = tid >> 6;
    const int n = lane & 15;  // output col within wave tile
    const int q = lane >> 4;  // k-subblock
    const int o = obase + wv * 16 + n;

    // issue deep packed prefetch FIRST so HBM latency hides under x-staging
    const int4* ppq = (const int4*)(packed + o * 2048 + (kbase >> 1)) + q;
    int4 P0 = ppq[0];
    int4 P1 = ppq[4];
    int4 P2 = ppq[8];
    int4 P3 = ppq[12];

    // per-lane group scales (8 floats, 32B contiguous) into registers
    const float4* sp = (const float4*)(scales + o * 64 + (kbase >> 6));
    float4 sA = sp[0], sB = sp[1];

    // dequant table: high 16 bits = bf16(hi-nibble code), low 16 = bf16(lo code)
    tbl[tid] = pk2(NF4_d[tid & 15], NF4_d[tid >> 4]);

    // stage x slice: 32 rows x 512 bf16
    for (int it = 0; it < 8; ++it) {
        int row = it * 4 + (tid >> 6);
        int c8 = tid & 63;
        *(uint4*)(xs + row * XPAD + c8 * 8) =
            *(const uint4*)(xbf + row * IN_F + kbase + c8 * 8);
    }
    __syncthreads();

    f32x4 acc0 = {0.f, 0.f, 0.f, 0.f};
    f32x4 acc1 = {0.f, 0.f, 0.f, 0.f};
    const u16* xr0 = xs + n * XPAD + q * 8;
    const u16* xr1 = xs + (n + 16) * XPAD + q * 8;

    int4 P[4] = {P0, P1, P2, P3};
    const float scr[8] = {sA.x, sA.y, sA.z, sA.w, sB.x, sB.y, sB.z, sB.w};

#pragma unroll
    for (int s = 0; s < 16; ++s) {
        int4 cur = P[s & 3];
        if (s + 4 < 16) P[s & 3] = ppq[(s + 4) * 4];
        float sc = scr[s >> 1];  // compile-time select (fully unrolled)

        unsigned u0 = tbl[cur.x & 255];
        unsigned u1 = tbl[cur.y & 255];
        unsigned u2 = tbl[cur.z & 255];
        unsigned u3 = tbl[cur.w & 255];
        uint4 bu;
        {
            float h = __int_as_float(u0 & 0xFFFF0000u);
            float l = __int_as_float(u0 << 16);
            bu.x = pk2(h * sc, l * sc);
        }
        {
            float h = __int_as_float(u1 & 0xFFFF0000u);
            float l = __int_as_float(u1 << 16);
            bu.y = pk2(h * sc, l * sc);
        }
        {
            float h = __int_as_float(u2 & 0xFFFF0000u);
            float l = __int_as_float(u2 << 16);
            bu.z = pk2(h * sc, l * sc);
        }
        {
            float h = __int_as_float(u3 & 0xFFFF0000u);
            float l = __int_as_float(u3 << 16);
            bu.w = pk2(h * sc, l * sc);
        }
        bf16x8 bfrag;
        __builtin_memcpy(&bfrag, &bu, 16);
        bf16x8 a0 = *(const bf16x8*)(xr0 + s * 32);
        bf16x8 a1 = *(const bf16x8*)(xr1 + s * 32);
        acc0 = __builtin_amdgcn_mfma_f32_16x16x32_bf16(a0, bfrag, acc0, 0, 0, 0);
        acc1 = __builtin_amdgcn_mfma_f32_16x16x32_bf16(a1, bfrag, acc1, 0, 0, 0);
    }

    // C/D layout: col = lane&15 (o), row = (lane>>4)*4 + reg (token)
    for (int r = 0; r < 4; ++r) {
        int t = q * 4 + r;
        atomicAdd(out + t * OUT_F + o, acc0[r]);
        atomicAdd(out + (t + 16) * OUT_F + o, acc1[r]);
    }
}

extern "C" void kernel_launch(void* const* d_in, const int* in_sizes, int n_in,
                              void* d_out, int out_size, void* d_ws, size_t ws_size,
                              hipStream_t stream) {
    const float* x = (const float*)d_in[0];
    const int* packed = (const int*)d_in[1];
    const float* scales = (const float*)d_in[2];
    const float* lora_A = (const float*)d_in[3];
    const float* lora_B = (const float*)d_in[4];
    float* out = (float*)d_out;

    u16* xbf = (u16*)d_ws;                                  // 262144 B
    float* xa = (float*)((char*)d_ws + 262144);             // 2048 B

    prep<<<640, 256, 0, stream>>>(x, lora_A, xbf, xa);
    lora_out<<<(TOKENS * OUT_F / 4) / 256, 256, 0, stream>>>(xa, lora_B, out);
    qlora_main<<<dim3(OUT_F / 64, KSPLIT), 256, 0, stream>>>(packed, scales, xbf, out);
}

// Round 5
// 152.682 us; speedup vs baseline: 1.0729x; 1.0384x over previous
//
#include <hip/hip_runtime.h>
#include <hip/hip_bf16.h>

#define IN_F 4096
#define OUT_F 11008
#define TOKENS 32
#define RANK 16
#define KSPLIT 8
#define KSLICE (IN_F / KSPLIT)  // 512
#define XPAD 520                // u16 per LDS x-row (512 data + 8 pad)
#define OUT_ELEMS (TOKENS * OUT_F)  // 352256

typedef unsigned short u16;
typedef __attribute__((ext_vector_type(8))) short bf16x8;
typedef __attribute__((ext_vector_type(4))) float f32x4;
typedef __attribute__((ext_vector_type(4))) int i32x4;

__device__ const float NF4_d[16] = {
    -1.0f, -0.6961928009986877f, -0.5250730514526367f, -0.39491748809814453f,
    -0.28444138169288635f, -0.18477343022823334f, -0.09105003625154495f, 0.0f,
    0.07958029955625534f, 0.16093020141124725f, 0.24611230194568634f,
    0.33791524171829224f, 0.44070982933044434f, 0.5626170039176941f,
    0.7229568362236023f, 1.0f};

static __device__ __forceinline__ unsigned pk2(float a, float b) {
    __hip_bfloat162 h = __float22bfloat162_rn(make_float2(a, b));
    unsigned u;
    __builtin_memcpy(&u, &h, 4);
    return u;
}

// kernel 1: blocks 0..511 compute xa[t][r]; blocks 512..575 zero out[]
__global__ void prep_xa_zero(const float* __restrict__ x, const float* __restrict__ A,
                             float* __restrict__ xa, float* __restrict__ out) {
    __shared__ float red[256];
    if (blockIdx.x >= 512) {
        int i = (blockIdx.x - 512) * 256 + threadIdx.x;  // 0..16383
        float4 z = make_float4(0.f, 0.f, 0.f, 0.f);
        for (int j = i; j < OUT_ELEMS / 4; j += 16384) ((float4*)out)[j] = z;
        return;
    }
    int b = blockIdx.x;  // 0..511
    int t = b >> 4, r = b & 15;
    const float4* xr = (const float4*)(x + t * IN_F);
    const float4* ar = (const float4*)(A + r * IN_F);
    float s = 0.f;
    for (int c = 0; c < 4; ++c) {
        int j = c * 256 + threadIdx.x;
        float4 xv = xr[j], av = ar[j];
        s += xv.x * av.x + xv.y * av.y + xv.z * av.z + xv.w * av.w;
    }
    red[threadIdx.x] = s;
    __syncthreads();
    for (int st = 128; st > 0; st >>= 1) {
        if (threadIdx.x < st) red[threadIdx.x] += red[threadIdx.x + st];
        __syncthreads();
    }
    if (threadIdx.x == 0) xa[b] = red[0];
}

// kernel 2: NF4 dequant + bf16 MFMA GEMM + fused lora epilogue (y==0 slice)
__global__ __launch_bounds__(256, 4) void qlora_fused(
    const int* __restrict__ packed, const float* __restrict__ scales,
    const float* __restrict__ x, const float* __restrict__ xa,
    const float* __restrict__ B, float* __restrict__ out) {
    __shared__ u16 xs[32 * XPAD];  // 32 tokens x 512 k (bf16), padded rows
    __shared__ unsigned tbl[256];  // byte -> packed bf16 (hi16=hi_code, lo16=lo_code)
    __shared__ float xal[512];     // xa staged (used by y==0 blocks only)
    const int tid = threadIdx.x;
    const int kbase = blockIdx.y * KSLICE;
    const int obase = blockIdx.x * 64;

    const int lane = tid & 63;
    const int wv = tid >> 6;
    const int n = lane & 15;  // output col within wave tile
    const int q = lane >> 4;  // k-subblock
    const int o = obase + wv * 16 + n;

    // deep packed prefetch FIRST (nontemporal: 90 MB single-use stream)
    const i32x4* ppq = (const i32x4*)(packed + o * 2048 + (kbase >> 1)) + q;
    i32x4 P[4];
    P[0] = __builtin_nontemporal_load(ppq);
    P[1] = __builtin_nontemporal_load(ppq + 4);
    P[2] = __builtin_nontemporal_load(ppq + 8);
    P[3] = __builtin_nontemporal_load(ppq + 12);

    // per-lane group scales (8 floats, 32B contiguous) into registers
    const float4* sp = (const float4*)(scales + o * 64 + (kbase >> 6));
    float4 sA = sp[0], sB = sp[1];

    // dequant table: hi16 = bf16(hi-nibble code), lo16 = bf16(lo-nibble code)
    tbl[tid] = pk2(NF4_d[tid & 15], NF4_d[tid >> 4]);

    if (blockIdx.y == 0) {  // stage xa for lora epilogue
        xal[tid] = xa[tid];
        xal[tid + 256] = xa[tid + 256];
    }

    // stage x slice: 32 rows x 512, fp32 -> bf16 during staging
    for (int it = 0; it < 8; ++it) {
        int row = it * 4 + (tid >> 6);
        int c8 = tid & 63;
        const float4* src = (const float4*)(x + row * IN_F + kbase + c8 * 8);
        float4 v0 = src[0], v1 = src[1];
        uint4 d;
        d.x = pk2(v0.x, v0.y);
        d.y = pk2(v0.z, v0.w);
        d.z = pk2(v1.x, v1.y);
        d.w = pk2(v1.z, v1.w);
        *(uint4*)(xs + row * XPAD + c8 * 8) = d;
    }
    __syncthreads();

    f32x4 acc0 = {0.f, 0.f, 0.f, 0.f};
    f32x4 acc1 = {0.f, 0.f, 0.f, 0.f};
    const u16* xr0 = xs + n * XPAD + q * 8;
    const u16* xr1 = xs + (n + 16) * XPAD + q * 8;
    const float scr[8] = {sA.x, sA.y, sA.z, sA.w, sB.x, sB.y, sB.z, sB.w};

#pragma unroll
    for (int s = 0; s < 16; ++s) {
        i32x4 cur = P[s & 3];
        if (s + 4 < 16) P[s & 3] = __builtin_nontemporal_load(ppq + (s + 4) * 4);
        float sc = scr[s >> 1];  // compile-time select (fully unrolled)

        unsigned u0 = tbl[cur[0] & 255];
        unsigned u1 = tbl[cur[1] & 255];
        unsigned u2 = tbl[cur[2] & 255];
        unsigned u3 = tbl[cur[3] & 255];
        uint4 bu;
        bu.x = pk2(__int_as_float(u0 & 0xFFFF0000u) * sc, __int_as_float(u0 << 16) * sc);
        bu.y = pk2(__int_as_float(u1 & 0xFFFF0000u) * sc, __int_as_float(u1 << 16) * sc);
        bu.z = pk2(__int_as_float(u2 & 0xFFFF0000u) * sc, __int_as_float(u2 << 16) * sc);
        bu.w = pk2(__int_as_float(u3 & 0xFFFF0000u) * sc, __int_as_float(u3 << 16) * sc);
        bf16x8 bfrag;
        __builtin_memcpy(&bfrag, &bu, 16);
        bf16x8 a0 = *(const bf16x8*)(xr0 + s * 32);
        bf16x8 a1 = *(const bf16x8*)(xr1 + s * 32);
        acc0 = __builtin_amdgcn_mfma_f32_16x16x32_bf16(a0, bfrag, acc0, 0, 0, 0);
        acc1 = __builtin_amdgcn_mfma_f32_16x16x32_bf16(a1, bfrag, acc1, 0, 0, 0);
    }

    // fused lora term (only the y==0 K-slice adds it)
    float lora[8] = {0.f, 0.f, 0.f, 0.f, 0.f, 0.f, 0.f, 0.f};
    if (blockIdx.y == 0) {
        const float4* br = (const float4*)(B + o * RANK);
        float4 b0 = br[0], b1 = br[1], b2 = br[2], b3 = br[3];
#pragma unroll
        for (int r = 0; r < 4; ++r) {
            const float* x0 = xal + (q * 4 + r) * RANK;
            const float* x1 = xal + (q * 4 + r + 16) * RANK;
            float s0 = 0.f, s1 = 0.f;
#pragma unroll
            for (int j = 0; j < 4; ++j) {
                const float4 bj = ((const float4*)&b0)[0];  // placeholder, unrolled below
            }
            s0 = b0.x * x0[0] + b0.y * x0[1] + b0.z * x0[2] + b0.w * x0[3] +
                 b1.x * x0[4] + b1.y * x0[5] + b1.z * x0[6] + b1.w * x0[7] +
                 b2.x * x0[8] + b2.y * x0[9] + b2.z * x0[10] + b2.w * x0[11] +
                 b3.x * x0[12] + b3.y * x0[13] + b3.z * x0[14] + b3.w * x0[15];
            s1 = b0.x * x1[0] + b0.y * x1[1] + b0.z * x1[2] + b0.w * x1[3] +
                 b1.x * x1[4] + b1.y * x1[5] + b1.z * x1[6] + b1.w * x1[7] +
                 b2.x * x1[8] + b2.y * x1[9] + b2.z * x1[10] + b2.w * x1[11] +
                 b3.x * x1[12] + b3.y * x1[13] + b3.z * x1[14] + b3.w * x1[15];
            lora[r] = s0;
            lora[r + 4] = s1;
        }
    }

    // C/D layout: col = lane&15 (o), row = (lane>>4)*4 + reg (token)
#pragma unroll
    for (int r = 0; r < 4; ++r) {
        int t = q * 4 + r;
        atomicAdd(out + t * OUT_F + o, acc0[r] + lora[r]);
        atomicAdd(out + (t + 16) * OUT_F + o, acc1[r] + lora[r + 4]);
    }
}

extern "C" void kernel_launch(void* const* d_in, const int* in_sizes, int n_in,
                              void* d_out, int out_size, void* d_ws, size_t ws_size,
                              hipStream_t stream) {
    const float* x = (const float*)d_in[0];
    const int* packed = (const int*)d_in[1];
    const float* scales = (const float*)d_in[2];
    const float* lora_A = (const float*)d_in[3];
    const float* lora_B = (const float*)d_in[4];
    float* out = (float*)d_out;

    float* xa = (float*)d_ws;  // 2048 B

    prep_xa_zero<<<576, 256, 0, stream>>>(x, lora_A, xa, out);
    qlora_fused<<<dim3(OUT_F / 64, KSPLIT), 256, 0, stream>>>(packed, scales, x, xa,
                                                              lora_B, out);
}